// Round 9
// baseline (97.445 us; speedup 1.0000x reference)
//
#include <hip/hip_runtime.h>
#include <hip/hip_bf16.h>

#define NB 1024
#define NH 256
#define EMB 128
#define TWOD 256
#define HID 256
#define CROWS 64            // rows per chunk
#define NCH 4               // chunks per batch element
#define HISTN 100000
#define REGN 1000

typedef __attribute__((ext_vector_type(4))) float f32x4;
typedef __attribute__((ext_vector_type(8))) short bf16x8;

__device__ __forceinline__ unsigned short f2bf(float f) {
  union { float f; unsigned u; } v; v.f = f;
  unsigned u = v.u;
  unsigned r = (u + 0x7fffu + ((u >> 16) & 1u)) >> 16;
  return (unsigned short)r;
}

__device__ __forceinline__ float bf2f(short s) {
  union { unsigned u; float f; } c;
  c.u = ((unsigned)(unsigned short)s) << 16;
  return c.f;
}

__device__ __forceinline__ bf16x8 pack8(f32x4 a, f32x4 b) {
  union { bf16x8 w; unsigned u[4]; } r;
  float2 p;
  union { __hip_bfloat162 h; unsigned u; } c;
  p.x = a[0]; p.y = a[1]; c.h = __float22bfloat162_rn(p); r.u[0] = c.u;
  p.x = a[2]; p.y = a[3]; c.h = __float22bfloat162_rn(p); r.u[1] = c.u;
  p.x = b[0]; p.y = b[1]; c.h = __float22bfloat162_rn(p); r.u[2] = c.u;
  p.x = b[2]; p.y = b[3]; c.h = __float22bfloat162_rn(p); r.u[3] = c.u;
  return r.w;
}

#define NE_H ((long long)HISTN * EMB)
#define NE_R ((long long)REGN * EMB)
#define EBF_BLOCKS ((int)((NE_H + NE_R + 2047) / 2048))   // 6313
#define PREP_BLOCKS (EBF_BLOCKS + TWOD)

// Fused prep: blocks [0, EBF_BLOCKS) convert E tables to bf16;
// blocks [EBF_BLOCKS, +256) build W1T [n][d] bf16.
__global__ __launch_bounds__(256) void prep_all(
    const float* __restrict__ W1, const float* __restrict__ Eh,
    const float* __restrict__ Er, unsigned short* __restrict__ W1T,
    unsigned short* __restrict__ EBH, unsigned short* __restrict__ EBR) {
  const int blk = blockIdx.x;
  if (blk < EBF_BLOCKS) {
    long long i = ((long long)blk * 256 + threadIdx.x) * 8;
    if (i >= NE_H + NE_R) return;
    const float* src; unsigned short* dst; long long off;
    if (i < NE_H) { src = Eh; dst = EBH; off = i; }
    else          { src = Er; dst = EBR; off = i - NE_H; }
    f32x4 v0 = *(const f32x4*)(src + off);
    f32x4 v1 = *(const f32x4*)(src + off + 4);
    *(bf16x8*)(dst + off) = pack8(v0, v1);
  } else {
    const int d = blk - EBF_BLOCKS;
    const int n = threadIdx.x;
    W1T[(size_t)n * TWOD + d] = f2bf(W1[(size_t)d * HID + n]);
  }
}

// 1024 blocks (1 per b), 512 threads = 8 waves, 4 pipelined chunks of 64 rows.
// Double-buffered bf16 panels; per-wave DMA ownership (wave DMAs and folds its
// own 8 rows -> per-wave vmcnt(0), no extra barrier). Per round:
//   GEMM(buf) | [pin] DMA(t+1 -> buf^1) [pin] | epilogue | bar |
//   vmcnt(0); fold(t+1) | wave0: exp(t) | bar
__global__ __launch_bounds__(512, 4) void nais_main(
    const int* __restrict__ history, const int* __restrict__ target,
    const int* __restrict__ hregion, const int* __restrict__ tregion,
    const float* __restrict__ E_targ, const float* __restrict__ E_reg,
    const unsigned short* __restrict__ EBH, const unsigned short* __restrict__ EBR,
    const unsigned short* __restrict__ W1T, const float* __restrict__ b1,
    const float* __restrict__ w2, float* __restrict__ out)
{
  const int b = blockIdx.x;
  const int tid = threadIdx.x;
  const int lane = tid & 63;
  const int wave = tid >> 6;            // 0..7
  const int l15 = lane & 15;
  const int lhi = lane >> 4;

  __shared__ __align__(16) unsigned short A_h[2][CROWS * EMB];  // 2 x 16 KiB
  __shared__ __align__(16) unsigned short A_r[2][CROWS * EMB];  // 2 x 16 KiB
  __shared__ __align__(16) float tgt_lds[TWOD];
  __shared__ int keys_h[NH];
  __shared__ int keys_r[NH];
  __shared__ float dot_lds[2][CROWS];
  __shared__ float score_parts[8][CROWS];

  const int tgt_item = target[b];

  // ---- prologue: all keys + target vector into LDS ----
  if (tid < NH) {
    keys_h[tid] = history[b * NH + tid];
    tgt_lds[tid] = (tid < EMB) ? E_targ[(size_t)target[b] * EMB + tid]
                               : E_reg[(size_t)tregion[b] * EMB + (tid - EMB)];
  } else {
    keys_r[tid - NH] = hregion[b * NH + (tid - NH)];
  }
  __syncthreads();

  // ---- wave-owned DMA: 8 rows (2 quads of 4) per panel, linear LDS dest,
  //      inverse-swizzled global source granule ----
  const int dma_r4 = lane >> 4;          // row within quad
  auto DMA_CHUNK = [&](int chunk, int bufsel) {
    #pragma unroll
    for (int q = 0; q < 2; ++q) {
      const int rl = q * 4 + dma_r4;                    // 0..7
      const int prow = wave * 8 + rl;
      const int g = (lane & 15) ^ rl;                   // prow&7 == rl
      const unsigned short* gh = EBH + (size_t)keys_h[chunk * CROWS + prow] * EMB + g * 8;
      __builtin_amdgcn_global_load_lds(
          (const __attribute__((address_space(1))) void*)gh,
          (__attribute__((address_space(3))) void*)&A_h[bufsel][(wave * 8 + q * 4) * EMB],
          16, 0, 0);
      const unsigned short* gr = EBR + (size_t)keys_r[chunk * CROWS + prow] * EMB + g * 8;
      __builtin_amdgcn_global_load_lds(
          (const __attribute__((address_space(1))) void*)gr,
          (__attribute__((address_space(3))) void*)&A_r[bufsel][(wave * 8 + q * 4) * EMB],
          16, 0, 0);
    }
  };

  // ---- fold: wave's own 8 rows; consecutive 8 lanes = 8 distinct rows
  //      -> 8 distinct bank groups (conflict-free) ----
  const int f_rl = lane & 7;
  const int f_seg = lane >> 3;           // 0..7
  const int f_pan = f_seg & 1;
  const int f_gb = (f_seg >> 1) * 4;     // 0,4,8,12
  auto FOLD_CHUNK = [&](int bufsel) {
    const int prow = wave * 8 + f_rl;
    unsigned short* panel = f_pan ? &A_r[bufsel][0] : &A_h[bufsel][0];
    float dsum = 0.f;
    #pragma unroll
    for (int j = 0; j < 4; ++j) {
      const int q = f_gb + j;
      const int gl = q ^ f_rl;           // prow&7 == f_rl
      bf16x8* ap = (bf16x8*)&panel[prow * EMB + gl * 8];
      bf16x8 a = *ap;
      const f32x4 t0 = *(const f32x4*)&tgt_lds[f_pan * EMB + q * 8];
      const f32x4 t1 = *(const f32x4*)&tgt_lds[f_pan * EMB + q * 8 + 4];
      f32x4 lo, hi;
      #pragma unroll
      for (int e = 0; e < 4; ++e) { lo[e] = bf2f(a[e]); hi[e] = bf2f(a[4 + e]); }
      lo *= t0; hi *= t1;
      dsum += lo[0] + lo[1] + lo[2] + lo[3] + hi[0] + hi[1] + hi[2] + hi[3];
      *ap = pack8(lo, hi);
    }
    dsum += __shfl_xor(dsum, 8);
    dsum += __shfl_xor(dsum, 16);
    dsum += __shfl_xor(dsum, 32);
    if (f_seg == 0) dot_lds[bufsel][prow] = dsum;
  };

  const int col0 = wave * 32;
  float b1v[2], w2v[2];
  #pragma unroll
  for (int n = 0; n < 2; ++n) {
    b1v[n] = b1[col0 + n * 16 + l15];
    w2v[n] = w2[col0 + n * 16 + l15];
  }

  // ---- pipeline prologue: chunk 0 ----
  DMA_CHUNK(0, 0);
  asm volatile("s_waitcnt vmcnt(0)" ::: "memory");
  __builtin_amdgcn_sched_barrier(0);
  FOLD_CHUNK(0);
  __syncthreads();

  float acc_e = 0.f, acc_ed = 0.f;       // wave 0 accumulators

  #pragma unroll
  for (int t = 0; t < NCH; ++t) {
    const int buf = t & 1;

    // ---- GEMM chunk t: wave's 32-col strip, kk outer ----
    f32x4 acc[4][2];
    #pragma unroll
    for (int m = 0; m < 4; ++m)
      #pragma unroll
      for (int n = 0; n < 2; ++n)
        acc[m][n] = (f32x4){0.f, 0.f, 0.f, 0.f};

    #pragma unroll
    for (int kk = 0; kk < 8; ++kk) {
      const unsigned short* panel = (kk < 4) ? &A_h[buf][0] : &A_r[buf][0];
      bf16x8 bfr[2];
      #pragma unroll
      for (int n = 0; n < 2; ++n)
        bfr[n] = *(const bf16x8*)(W1T + (size_t)(col0 + n * 16 + l15) * TWOD + kk * 32 + lhi * 8);
      bf16x8 af[4];
      #pragma unroll
      for (int m = 0; m < 4; ++m) {
        const int row = m * 16 + l15;
        const int gk = ((kk & 3) * 4 + lhi) ^ (row & 7);
        af[m] = *(const bf16x8*)&panel[row * EMB + gk * 8];
      }
      __builtin_amdgcn_s_setprio(1);
      #pragma unroll
      for (int m = 0; m < 4; ++m)
        #pragma unroll
        for (int n = 0; n < 2; ++n)
          acc[m][n] = __builtin_amdgcn_mfma_f32_16x16x32_bf16(af[m], bfr[n], acc[m][n], 0, 0, 0);
      __builtin_amdgcn_s_setprio(0);
    }

    // ---- issue next chunk's DMA here: latency hides under epilogue+bar+fold.
    //      sched_barrier pins it after all bfr loads so compiler's counted
    //      vmcnt waits for bfr never drain the DMA queue. ----
    if (t < NCH - 1) {
      __builtin_amdgcn_sched_barrier(0);
      DMA_CHUNK(t + 1, buf ^ 1);
      __builtin_amdgcn_sched_barrier(0);
    }

    // ---- epilogue: relu + b1, dot w2, 16-lane reduce -> score_parts ----
    #pragma unroll
    for (int m = 0; m < 4; ++m) {
      #pragma unroll
      for (int r = 0; r < 4; ++r) {
        float p = 0.f;
        #pragma unroll
        for (int n = 0; n < 2; ++n) {
          float hv = acc[m][n][r] + b1v[n];   // C/D: col=lane&15, row=(lane>>4)*4+r
          hv = hv > 0.f ? hv : 0.f;
          p += hv * w2v[n];
        }
        p += __shfl_xor(p, 1);
        p += __shfl_xor(p, 2);
        p += __shfl_xor(p, 4);
        p += __shfl_xor(p, 8);
        if (l15 == 0) score_parts[wave][m * 16 + lhi * 4 + r] = p;
      }
    }
    __syncthreads();

    // ---- fold next chunk (own rows; own DMA -> per-wave vmcnt suffices) ----
    if (t < NCH - 1) {
      asm volatile("s_waitcnt vmcnt(0)" ::: "memory");
      __builtin_amdgcn_sched_barrier(0);
      FOLD_CHUNK(buf ^ 1);
    }

    // ---- wave 0: masked exp fold of chunk t ----
    if (wave == 0) {
      float sc = 0.f;
      #pragma unroll
      for (int w = 0; w < 8; ++w) sc += score_parts[w][lane];
      const float e = (keys_h[t * CROWS + lane] != tgt_item) ? expf(sc) : 0.f;
      acc_e += e;
      acc_ed += e * dot_lds[buf][lane];
    }
    if (t < NCH - 1) __syncthreads();
  }

  // ---- wave 0: final reduce + sigmoid ----
  if (wave == 0) {
    float se = acc_e, sd = acc_ed;
    #pragma unroll
    for (int off = 32; off >= 1; off >>= 1) {
      se += __shfl_xor(se, off);
      sd += __shfl_xor(sd, off);
    }
    if (lane == 0) {
      const float pred = (se > 0.f) ? (sd / sqrtf(se)) : 0.f;  // denom = sum^0.5
      out[b] = 1.f / (1.f + expf(-pred));
    }
  }
}

extern "C" void kernel_launch(void* const* d_in, const int* in_sizes, int n_in,
                              void* d_out, int out_size, void* d_ws, size_t ws_size,
                              hipStream_t stream) {
  const int* history = (const int*)d_in[0];
  const int* target  = (const int*)d_in[1];
  const int* hregion = (const int*)d_in[2];
  const int* tregion = (const int*)d_in[3];
  const float* E_hist = (const float*)d_in[4];
  const float* E_targ = (const float*)d_in[5];
  const float* E_reg  = (const float*)d_in[6];
  const float* W1 = (const float*)d_in[7];
  const float* b1 = (const float*)d_in[8];
  const float* w2 = (const float*)d_in[9];
  float* out = (float*)d_out;

  char* p = (char*)d_ws;
  unsigned short* W1T = (unsigned short*)p;  p += (size_t)TWOD * HID * 2;   // 128 KB
  unsigned short* EBR = (unsigned short*)p;  p += (size_t)REGN * EMB * 2;   // 256 KB
  unsigned short* EBH = (unsigned short*)p;                                  // 25.6 MB

  prep_all<<<PREP_BLOCKS, 256, 0, stream>>>(W1, E_hist, E_reg, W1T, EBH, EBR);
  nais_main<<<NB, 512, 0, stream>>>(history, target, hregion, tregion,
                                    E_targ, E_reg, EBH, EBR, W1T, b1, w2, out);
}